// Round 1
// baseline (141.164 us; speedup 1.0000x reference)
//
#include <hip/hip_runtime.h>
#include <math.h>

// Box-embedding conditional-probability loss.
// Per sample: gather 4 rows (min/delta for t1,t2) of D=128 fp32, compute
// join/meet boxes, 4 log-volume reductions, final pos/neg losses.
// Mapping: 32 lanes per sample, each lane owns one float4 (4 dims) of the
// 128-dim row -> each row load is one coalesced 512B access.

#define EPSF 1e-8f

__global__ __launch_bounds__(256) void box_loss_kernel(
    const int* __restrict__ t1x, const int* __restrict__ t2x,
    const float* __restrict__ min_t, const float* __restrict__ delta_t,
    float* __restrict__ out, int B)
{
    // constants rounded from double, matching numpy/jax f32 behavior
    const float MIN_MEAN   = (float)((0.0001 + 0.01) / 2.0);          // 0.00505
    const float MIN_VAR    = (float)(0.01 - (0.0001 + 0.01) / 2.0);   // 0.00495
    const float DELTA_MEAN = (float)((0.9 + 0.999) / 2.0);            // 0.9495
    const float DELTA_VAR  = (float)(0.999 - (0.9 + 0.999) / 2.0);    // 0.0495

    int gid  = blockIdx.x * blockDim.x + threadIdx.x;
    int s    = gid >> 5;            // sample index: one 32-lane group per sample
    int lane = threadIdx.x & 31;
    if (s >= B) return;

    long i1 = (long)t1x[s];
    long i2 = (long)t2x[s];

    const float4* m1 = reinterpret_cast<const float4*>(min_t   + i1 * 128);
    const float4* d1 = reinterpret_cast<const float4*>(delta_t + i1 * 128);
    const float4* m2 = reinterpret_cast<const float4*>(min_t   + i2 * 128);
    const float4* d2 = reinterpret_cast<const float4*>(delta_t + i2 * 128);

    float4 vm1 = m1[lane];
    float4 vd1 = d1[lane];
    float4 vm2 = m2[lane];
    float4 vd2 = d2[lane];

    const float* pm1 = reinterpret_cast<const float*>(&vm1);
    const float* pd1 = reinterpret_cast<const float*>(&vd1);
    const float* pm2 = reinterpret_cast<const float*>(&vm2);
    const float* pd2 = reinterpret_cast<const float*>(&vd2);

    float t1_log = 0.f, t2_log = 0.f, meet_log = 0.f, join_log = 0.f;
    int disjoint = 0;

    #pragma unroll
    for (int k = 0; k < 4; ++k) {
        float t1min = fmaf(pm1[k], MIN_VAR, MIN_MEAN);
        float t1dl  = fmaf(pd1[k], DELTA_VAR, DELTA_MEAN);
        float t1max = t1min + t1dl;

        float t2min = fmaf(pm2[k], MIN_VAR, MIN_MEAN);
        float t2dl  = fmaf(pd2[k], DELTA_VAR, DELTA_MEAN);
        float t2max = t2min + t2dl;

        float jm = fminf(t1min, t2min);
        float jM = fmaxf(t1max, t2max);
        float mm = fmaxf(t1min, t2min);
        float mM = fminf(t1max, t2max);

        disjoint |= (mM <= mm) ? 1 : 0;

        t1_log   += __logf(fmaxf(t1max - t1min, EPSF));
        t2_log   += __logf(fmaxf(t2max - t2min, EPSF));
        meet_log += __logf(fmaxf(mM - mm, EPSF));
        join_log += __logf(fmaxf(jM - jm, EPSF));
    }

    // butterfly reduce across the 32-lane group (masks < 32 stay in-half)
    #pragma unroll
    for (int m = 16; m >= 1; m >>= 1) {
        t1_log   += __shfl_xor(t1_log,   m, 64);
        t2_log   += __shfl_xor(t2_log,   m, 64);
        meet_log += __shfl_xor(meet_log, m, 64);
        join_log += __shfl_xor(join_log, m, 64);
        disjoint |= __shfl_xor(disjoint, m, 64);
    }

    if (lane == 0) {
        float cond = meet_log - t2_log;
        float pos, neg;
        if (disjoint) {
            pos = join_log - t1_log;       // -(t1_log - join_log)
            neg = 0.f;
        } else {
            pos = -cond;
            // precise path: cancellation near cond==0
            neg = -logf(fmaxf(1.f - expf(cond), EPSF));
        }
        out[s]     = pos;   // train_pos_prob
        out[B + s] = neg;   // train_neg_prob
    }
}

extern "C" void kernel_launch(void* const* d_in, const int* in_sizes, int n_in,
                              void* d_out, int out_size, void* d_ws, size_t ws_size,
                              hipStream_t stream) {
    const int*   t1x     = (const int*)d_in[0];
    const int*   t2x     = (const int*)d_in[1];
    const float* min_t   = (const float*)d_in[2];
    const float* delta_t = (const float*)d_in[3];
    float*       out     = (float*)d_out;

    int B = in_sizes[0];
    int threads = 256;                       // 8 samples per block
    int blocks  = (B * 32 + threads - 1) / threads;
    box_loss_kernel<<<blocks, threads, 0, stream>>>(t1x, t2x, min_t, delta_t, out, B);
}

// Round 2
// 137.380 us; speedup vs baseline: 1.0275x; 1.0275x over previous
//
#include <hip/hip_runtime.h>
#include <math.h>

// Box-embedding conditional-probability loss.
// R2: 8 lanes/sample x 16 dims/lane (was 32x4).
//  - log-of-product: 4 logs/lane instead of 16 (transcendental is 1/4-rate)
//  - widths from the affine delta directly (no t1max-t1min subs for volumes)
//  - disjoint via running fminf of meet width (no cmp/or per dim)
//  - 3-step butterfly reduce instead of 5
// Loads: lane l of a sample reads float4 chunk c*8+l -> 8 lanes x 16B = 128B
// contiguous per row per instruction; 16 loads/lane issued up front for MLP.

#define EPSF 1e-8f

__global__ __launch_bounds__(256) void box_loss_kernel(
    const int* __restrict__ t1x, const int* __restrict__ t2x,
    const float* __restrict__ min_t, const float* __restrict__ delta_t,
    float* __restrict__ out, int B)
{
    const float MIN_MEAN   = (float)((0.0001 + 0.01) / 2.0);          // 0.00505
    const float MIN_VAR    = (float)(0.01 - (0.0001 + 0.01) / 2.0);   // 0.00495
    const float DELTA_MEAN = (float)((0.9 + 0.999) / 2.0);            // 0.9495
    const float DELTA_VAR  = (float)(0.999 - (0.9 + 0.999) / 2.0);    // 0.0495

    int gid  = blockIdx.x * blockDim.x + threadIdx.x;
    int s    = gid >> 3;            // one 8-lane group per sample
    int lane = threadIdx.x & 7;
    if (s >= B) return;

    size_t i1 = (size_t)t1x[s];
    size_t i2 = (size_t)t2x[s];

    const float4* m1 = reinterpret_cast<const float4*>(min_t   + i1 * 128);
    const float4* d1 = reinterpret_cast<const float4*>(delta_t + i1 * 128);
    const float4* m2 = reinterpret_cast<const float4*>(min_t   + i2 * 128);
    const float4* d2 = reinterpret_cast<const float4*>(delta_t + i2 * 128);

    // load all 16 float4s up front (4 chunks x 4 rows) for latency hiding
    float4 a1[4], b1[4], a2[4], b2[4];
    #pragma unroll
    for (int c = 0; c < 4; ++c) {
        int off = c * 8 + lane;
        a1[c] = m1[off];
        b1[c] = d1[off];
        a2[c] = m2[off];
        b2[c] = d2[off];
    }

    float p1 = 1.f, p2 = 1.f, pm = 1.f, pj = 1.f;
    float wmin = 1e30f;   // running min of meet width -> disjoint iff <= 0

    #pragma unroll
    for (int c = 0; c < 4; ++c) {
        const float* pa1 = reinterpret_cast<const float*>(&a1[c]);
        const float* pb1 = reinterpret_cast<const float*>(&b1[c]);
        const float* pa2 = reinterpret_cast<const float*>(&a2[c]);
        const float* pb2 = reinterpret_cast<const float*>(&b2[c]);
        #pragma unroll
        for (int k = 0; k < 4; ++k) {
            float t1min = fmaf(pa1[k], MIN_VAR, MIN_MEAN);
            float w1    = fmaf(pb1[k], DELTA_VAR, DELTA_MEAN);
            float t2min = fmaf(pa2[k], MIN_VAR, MIN_MEAN);
            float w2    = fmaf(pb2[k], DELTA_VAR, DELTA_MEAN);
            float t1max = t1min + w1;
            float t2max = t2min + w2;

            float mm_ = fmaxf(t1min, t2min);
            float mM_ = fminf(t1max, t2max);
            float jm_ = fminf(t1min, t2min);
            float jM_ = fmaxf(t1max, t2max);

            float wm = mM_ - mm_;           // meet width (may be <= 0)
            float wj = jM_ - jm_;           // join width (>= w1 > 0)

            wmin = fminf(wmin, wm);
            p1 *= w1;                       // w1,w2 ~ 0.95 +- 0.05*N(0,1): > 0
            p2 *= w2;
            pm *= fmaxf(wm, EPSF);
            pj *= wj;
        }
    }

    // one log per quantity per lane (products of 16 widths: ~[0.2, 2], safe)
    float l1 = __logf(p1);
    float l2 = __logf(p2);
    float lm = __logf(pm);
    float lj = __logf(pj);

    // butterfly across the 8-lane group (masks 4,2,1 stay in-group)
    #pragma unroll
    for (int m = 4; m >= 1; m >>= 1) {
        l1   += __shfl_xor(l1,   m, 64);
        l2   += __shfl_xor(l2,   m, 64);
        lm   += __shfl_xor(lm,   m, 64);
        lj   += __shfl_xor(lj,   m, 64);
        wmin  = fminf(wmin, __shfl_xor(wmin, m, 64));
    }

    if (lane == 0) {
        float cond = lm - l2;
        float pos, neg;
        if (wmin <= 0.f) {                  // disjoint
            pos = lj - l1;                  // -(t1_log - join_log)
            neg = 0.f;
        } else {
            pos = -cond;
            // precise path: cancellation near cond==0
            neg = -logf(fmaxf(1.f - expf(cond), EPSF));
        }
        out[s]     = pos;   // train_pos_prob
        out[B + s] = neg;   // train_neg_prob
    }
}

extern "C" void kernel_launch(void* const* d_in, const int* in_sizes, int n_in,
                              void* d_out, int out_size, void* d_ws, size_t ws_size,
                              hipStream_t stream) {
    const int*   t1x     = (const int*)d_in[0];
    const int*   t2x     = (const int*)d_in[1];
    const float* min_t   = (const float*)d_in[2];
    const float* delta_t = (const float*)d_in[3];
    float*       out     = (float*)d_out;

    int B = in_sizes[0];
    int threads = 256;                       // 32 samples per block
    int blocks  = (B * 8 + threads - 1) / threads;
    box_loss_kernel<<<blocks, threads, 0, stream>>>(t1x, t2x, min_t, delta_t, out, B);
}

// Round 3
// 136.097 us; speedup vs baseline: 1.0372x; 1.0094x over previous
//
#include <hip/hip_runtime.h>
#include <math.h>

// Box-embedding conditional-probability loss.
// R3: same math as R2 (log-of-product, 8 lanes/sample x 16 dims/lane), but
// force ALL 16 float4 gathers to issue before any compute via
// sched_barrier(0). R2's VGPR_Count=36 proved the compiler sank the loads
// into the compute loop (~4-5 in flight instead of 16) -> latency-bound with
// every pipe idle (VALU 21%, HBM 38%). Trading occupancy (VGPR ~80, 4
// waves/SIMD) for 4x memory-level parallelism per wave.

#define EPSF 1e-8f

__global__ __launch_bounds__(256) void box_loss_kernel(
    const int* __restrict__ t1x, const int* __restrict__ t2x,
    const float* __restrict__ min_t, const float* __restrict__ delta_t,
    float* __restrict__ out, int B)
{
    const float MIN_MEAN   = (float)((0.0001 + 0.01) / 2.0);          // 0.00505
    const float MIN_VAR    = (float)(0.01 - (0.0001 + 0.01) / 2.0);   // 0.00495
    const float DELTA_MEAN = (float)((0.9 + 0.999) / 2.0);            // 0.9495
    const float DELTA_VAR  = (float)(0.999 - (0.9 + 0.999) / 2.0);    // 0.0495

    int gid  = blockIdx.x * blockDim.x + threadIdx.x;
    int s    = gid >> 3;            // one 8-lane group per sample
    int lane = threadIdx.x & 7;
    if (s >= B) return;

    size_t i1 = (size_t)t1x[s];
    size_t i2 = (size_t)t2x[s];

    const float4* m1 = reinterpret_cast<const float4*>(min_t   + i1 * 128);
    const float4* d1 = reinterpret_cast<const float4*>(delta_t + i1 * 128);
    const float4* m2 = reinterpret_cast<const float4*>(min_t   + i2 * 128);
    const float4* d2 = reinterpret_cast<const float4*>(delta_t + i2 * 128);

    // Issue ALL 16 gathers before any compute; sched_barrier(0) pins them.
    float4 a1[4], b1[4], a2[4], b2[4];
    #pragma unroll
    for (int c = 0; c < 4; ++c) {
        int off = c * 8 + lane;
        a1[c] = m1[off];
        b1[c] = d1[off];
        a2[c] = m2[off];
        b2[c] = d2[off];
    }
#if defined(__has_builtin)
#if __has_builtin(__builtin_amdgcn_sched_barrier)
    __builtin_amdgcn_sched_barrier(0);   // no instr may cross: all loads stay above
#endif
#endif

    float p1 = 1.f, p2 = 1.f, pm = 1.f, pj = 1.f;
    float wmin = 1e30f;   // running min of meet width -> disjoint iff <= 0

    #pragma unroll
    for (int c = 0; c < 4; ++c) {
        const float* pa1 = reinterpret_cast<const float*>(&a1[c]);
        const float* pb1 = reinterpret_cast<const float*>(&b1[c]);
        const float* pa2 = reinterpret_cast<const float*>(&a2[c]);
        const float* pb2 = reinterpret_cast<const float*>(&b2[c]);
        #pragma unroll
        for (int k = 0; k < 4; ++k) {
            float t1min = fmaf(pa1[k], MIN_VAR, MIN_MEAN);
            float w1    = fmaf(pb1[k], DELTA_VAR, DELTA_MEAN);
            float t2min = fmaf(pa2[k], MIN_VAR, MIN_MEAN);
            float w2    = fmaf(pb2[k], DELTA_VAR, DELTA_MEAN);
            float t1max = t1min + w1;
            float t2max = t2min + w2;

            float mm_ = fmaxf(t1min, t2min);
            float mM_ = fminf(t1max, t2max);
            float jm_ = fminf(t1min, t2min);
            float jM_ = fmaxf(t1max, t2max);

            float wm = mM_ - mm_;           // meet width (may be <= 0)
            float wj = jM_ - jm_;           // join width (>= w1 > 0)

            wmin = fminf(wmin, wm);
            p1 *= w1;                       // w1,w2 ~ 0.95 +- 0.05*N(0,1): > 0
            p2 *= w2;
            pm *= fmaxf(wm, EPSF);
            pj *= wj;
        }
    }

    // one log per quantity per lane (products of 16 widths: ~[0.2, 2], safe)
    float l1 = __logf(p1);
    float l2 = __logf(p2);
    float lm = __logf(pm);
    float lj = __logf(pj);

    // butterfly across the 8-lane group (masks 4,2,1 stay in-group)
    #pragma unroll
    for (int m = 4; m >= 1; m >>= 1) {
        l1   += __shfl_xor(l1,   m, 64);
        l2   += __shfl_xor(l2,   m, 64);
        lm   += __shfl_xor(lm,   m, 64);
        lj   += __shfl_xor(lj,   m, 64);
        wmin  = fminf(wmin, __shfl_xor(wmin, m, 64));
    }

    if (lane == 0) {
        float cond = lm - l2;
        float pos, neg;
        if (wmin <= 0.f) {                  // disjoint
            pos = lj - l1;                  // -(t1_log - join_log)
            neg = 0.f;
        } else {
            pos = -cond;
            // precise path: cancellation near cond==0
            neg = -logf(fmaxf(1.f - expf(cond), EPSF));
        }
        out[s]     = pos;   // train_pos_prob
        out[B + s] = neg;   // train_neg_prob
    }
}

extern "C" void kernel_launch(void* const* d_in, const int* in_sizes, int n_in,
                              void* d_out, int out_size, void* d_ws, size_t ws_size,
                              hipStream_t stream) {
    const int*   t1x     = (const int*)d_in[0];
    const int*   t2x     = (const int*)d_in[1];
    const float* min_t   = (const float*)d_in[2];
    const float* delta_t = (const float*)d_in[3];
    float*       out     = (float*)d_out;

    int B = in_sizes[0];
    int threads = 256;                       // 32 samples per block
    int blocks  = (B * 8 + threads - 1) / threads;
    box_loss_kernel<<<blocks, threads, 0, stream>>>(t1x, t2x, min_t, delta_t, out, B);
}

// Round 4
// 135.970 us; speedup vs baseline: 1.0382x; 1.0009x over previous
//
#include <hip/hip_runtime.h>
#include <math.h>

// Box-embedding conditional-probability loss.
// R4: MLP falsification experiment. R3's sched_barrier was defeated by the
// occupancy-targeting scheduler (VGPR stayed 36 -> loads still sunk into the
// compute loop). __launch_bounds__(256, 4) sets amdgpu-waves-per-eu=4,
// raising the register-pressure cap to ~128 VGPRs so the prefetch-all-16
// structure can actually materialize (~64 VGPRs of payload in flight).
// Primary theory says we're fabric-bandwidth-bound (246MB cross-XCD /
// 41.5us = 5.9 TB/s ~= the 6.3 TB/s copy ceiling): predict dur UNCHANGED,
// VGPR 80-110, occupancy ~30-40%. If dur <= 39us, latency model revives.

#define EPSF 1e-8f

__global__ __launch_bounds__(256, 4) void box_loss_kernel(
    const int* __restrict__ t1x, const int* __restrict__ t2x,
    const float* __restrict__ min_t, const float* __restrict__ delta_t,
    float* __restrict__ out, int B)
{
    const float MIN_MEAN   = (float)((0.0001 + 0.01) / 2.0);          // 0.00505
    const float MIN_VAR    = (float)(0.01 - (0.0001 + 0.01) / 2.0);   // 0.00495
    const float DELTA_MEAN = (float)((0.9 + 0.999) / 2.0);            // 0.9495
    const float DELTA_VAR  = (float)(0.999 - (0.9 + 0.999) / 2.0);    // 0.0495

    int gid  = blockIdx.x * blockDim.x + threadIdx.x;
    int s    = gid >> 3;            // one 8-lane group per sample
    int lane = threadIdx.x & 7;
    if (s >= B) return;

    size_t i1 = (size_t)t1x[s];
    size_t i2 = (size_t)t2x[s];

    const float4* m1 = reinterpret_cast<const float4*>(min_t   + i1 * 128);
    const float4* d1 = reinterpret_cast<const float4*>(delta_t + i1 * 128);
    const float4* m2 = reinterpret_cast<const float4*>(min_t   + i2 * 128);
    const float4* d2 = reinterpret_cast<const float4*>(delta_t + i2 * 128);

    // Issue ALL 16 gathers before any compute; sched_barrier(0) pins them,
    // and waves-per-eu=4 gives the scheduler the register budget to comply.
    float4 a1[4], b1[4], a2[4], b2[4];
    #pragma unroll
    for (int c = 0; c < 4; ++c) {
        int off = c * 8 + lane;
        a1[c] = m1[off];
        b1[c] = d1[off];
        a2[c] = m2[off];
        b2[c] = d2[off];
    }
#if defined(__has_builtin)
#if __has_builtin(__builtin_amdgcn_sched_barrier)
    __builtin_amdgcn_sched_barrier(0);   // no instr may cross: loads stay above
#endif
#endif

    float p1 = 1.f, p2 = 1.f, pm = 1.f, pj = 1.f;
    float wmin = 1e30f;   // running min of meet width -> disjoint iff <= 0

    #pragma unroll
    for (int c = 0; c < 4; ++c) {
        const float* pa1 = reinterpret_cast<const float*>(&a1[c]);
        const float* pb1 = reinterpret_cast<const float*>(&b1[c]);
        const float* pa2 = reinterpret_cast<const float*>(&a2[c]);
        const float* pb2 = reinterpret_cast<const float*>(&b2[c]);
        #pragma unroll
        for (int k = 0; k < 4; ++k) {
            float t1min = fmaf(pa1[k], MIN_VAR, MIN_MEAN);
            float w1    = fmaf(pb1[k], DELTA_VAR, DELTA_MEAN);
            float t2min = fmaf(pa2[k], MIN_VAR, MIN_MEAN);
            float w2    = fmaf(pb2[k], DELTA_VAR, DELTA_MEAN);
            float t1max = t1min + w1;
            float t2max = t2min + w2;

            float mm_ = fmaxf(t1min, t2min);
            float mM_ = fminf(t1max, t2max);
            float jm_ = fminf(t1min, t2min);
            float jM_ = fmaxf(t1max, t2max);

            float wm = mM_ - mm_;           // meet width (may be <= 0)
            float wj = jM_ - jm_;           // join width (>= w1 > 0)

            wmin = fminf(wmin, wm);
            p1 *= w1;                       // w1,w2 ~ 0.95 +- 0.05*N(0,1): > 0
            p2 *= w2;
            pm *= fmaxf(wm, EPSF);
            pj *= wj;
        }
    }

    // one log per quantity per lane (products of 16 widths: ~[0.2, 2], safe)
    float l1 = __logf(p1);
    float l2 = __logf(p2);
    float lm = __logf(pm);
    float lj = __logf(pj);

    // butterfly across the 8-lane group (masks 4,2,1 stay in-group)
    #pragma unroll
    for (int m = 4; m >= 1; m >>= 1) {
        l1   += __shfl_xor(l1,   m, 64);
        l2   += __shfl_xor(l2,   m, 64);
        lm   += __shfl_xor(lm,   m, 64);
        lj   += __shfl_xor(lj,   m, 64);
        wmin  = fminf(wmin, __shfl_xor(wmin, m, 64));
    }

    if (lane == 0) {
        float cond = lm - l2;
        float pos, neg;
        if (wmin <= 0.f) {                  // disjoint
            pos = lj - l1;                  // -(t1_log - join_log)
            neg = 0.f;
        } else {
            pos = -cond;
            // precise path: cancellation near cond==0
            neg = -logf(fmaxf(1.f - expf(cond), EPSF));
        }
        out[s]     = pos;   // train_pos_prob
        out[B + s] = neg;   // train_neg_prob
    }
}

extern "C" void kernel_launch(void* const* d_in, const int* in_sizes, int n_in,
                              void* d_out, int out_size, void* d_ws, size_t ws_size,
                              hipStream_t stream) {
    const int*   t1x     = (const int*)d_in[0];
    const int*   t2x     = (const int*)d_in[1];
    const float* min_t   = (const float*)d_in[2];
    const float* delta_t = (const float*)d_in[3];
    float*       out     = (float*)d_out;

    int B = in_sizes[0];
    int threads = 256;                       // 32 samples per block
    int blocks  = (B * 8 + threads - 1) / threads;
    box_loss_kernel<<<blocks, threads, 0, stream>>>(t1x, t2x, min_t, delta_t, out, B);
}